// Round 1
// baseline (2038.946 us; speedup 1.0000x reference)
//
#include <hip/hip_runtime.h>
#include <math.h>

#define B_ 4
#define S_ 2048
#define H_ 512
#define HEADS_ 8
#define DK_ 64
#define NROWS_ (B_*S_)          // 8192
#define LN_EPS_ 1e-5f
#define NEG_INF_ -1e30f

#define KTILE 32
#define QTILE 128

// ---------------------------------------------------------------------------
// Kernel 1: LayerNorm. One block per row of 512; 256 threads, 2 elems each.
// ---------------------------------------------------------------------------
__global__ __launch_bounds__(256) void ln_kernel(
        const float* __restrict__ x, const float* __restrict__ gamma,
        const float* __restrict__ beta, float* __restrict__ xn) {
    int row = blockIdx.x;
    const float* xr = x + (size_t)row * H_;
    int t = threadIdx.x;
    float v0 = xr[t], v1 = xr[t + 256];
    float s = v0 + v1, ss = v0 * v0 + v1 * v1;
    #pragma unroll
    for (int i = 1; i < 64; i <<= 1) {
        s  += __shfl_xor(s, i, 64);
        ss += __shfl_xor(ss, i, 64);
    }
    __shared__ float red[8];
    int w = t >> 6, lane = t & 63;
    if (lane == 0) { red[w] = s; red[w + 4] = ss; }
    __syncthreads();
    s  = red[0] + red[1] + red[2] + red[3];
    ss = red[4] + red[5] + red[6] + red[7];
    float mu  = s * (1.f / 512.f);
    float var = ss * (1.f / 512.f) - mu * mu;
    float rstd = rsqrtf(var + LN_EPS_);
    size_t o = (size_t)row * H_;
    xn[o + t]       = (v0 - mu) * rstd * gamma[t]       + beta[t];
    xn[o + t + 256] = (v1 - mu) * rstd * gamma[t + 256] + beta[t + 256];
}

// ---------------------------------------------------------------------------
// Kernel 2: QKV projection. C(8192x512) = xn @ W per head, 64x64 tiles.
// grid (8 heads/colblocks, 128 rowblocks, 3 {Q,K,V}); block 256 = 16x16, 4x4
// micro-tile. Output layout (B, HEADS, S, DK).
// ---------------------------------------------------------------------------
__global__ __launch_bounds__(256) void qkv_kernel(
        const float* __restrict__ xn,
        const float* __restrict__ Wq, const float* __restrict__ Wk,
        const float* __restrict__ Wv,
        float* __restrict__ Q, float* __restrict__ K, float* __restrict__ V) {
    const float* W = (blockIdx.z == 0) ? Wq : (blockIdx.z == 1) ? Wk : Wv;
    float* Out = (blockIdx.z == 0) ? Q : (blockIdx.z == 1) ? K : V;
    int n = blockIdx.x;                // head index; col block = n*64
    int row0 = blockIdx.y * 64;
    __shared__ float As[16][65];
    __shared__ float Bs[16][65];
    int t = threadIdx.x;
    int tx = t & 15, ty = t >> 4;
    float acc[4][4] = {};
    const float* Wn = W + (size_t)n * H_ * DK_;   // [h][d], 512x64 row-major
    for (int k0 = 0; k0 < H_; k0 += 16) {
        #pragma unroll
        for (int i = 0; i < 4; i++) {
            int idx = t + i * 256;
            int c = idx & 15, r = idx >> 4;
            As[c][r] = xn[(size_t)(row0 + r) * H_ + k0 + c];
        }
        #pragma unroll
        for (int i = 0; i < 4; i++) {
            int idx = t + i * 256;
            int d = idx & 63, kk = idx >> 6;
            Bs[kk][d] = Wn[(size_t)(k0 + kk) * DK_ + d];
        }
        __syncthreads();
        #pragma unroll
        for (int kk = 0; kk < 16; kk++) {
            float a[4], bb[4];
            #pragma unroll
            for (int i = 0; i < 4; i++) a[i] = As[kk][ty * 4 + i];
            #pragma unroll
            for (int j = 0; j < 4; j++) bb[j] = Bs[kk][tx * 4 + j];
            #pragma unroll
            for (int i = 0; i < 4; i++)
                #pragma unroll
                for (int j = 0; j < 4; j++) acc[i][j] += a[i] * bb[j];
        }
        __syncthreads();
    }
    #pragma unroll
    for (int i = 0; i < 4; i++) {
        int r = row0 + ty * 4 + i;
        int b = r >> 11, srow = r & 2047;
        size_t base = (((size_t)(b * HEADS_ + n)) * S_ + srow) * DK_ + tx * 4;
        #pragma unroll
        for (int j = 0; j < 4; j++) Out[base + j] = acc[i][j];
    }
}

// ---------------------------------------------------------------------------
// Kernel 3: flash attention, fp32. One q-row per lane; K/V tiles of 32 keys
// staged in LDS (broadcast float4 reads); per-thread online softmax.
// grid (S/QTILE, B*HEADS); block QTILE=128.
// ---------------------------------------------------------------------------
__global__ __launch_bounds__(128, 2) void attn_kernel(
        const float* __restrict__ Q, const float* __restrict__ K,
        const float* __restrict__ V, const int* __restrict__ mask,
        float* __restrict__ Hout) {
    int bh = blockIdx.y;
    int b = bh >> 3;
    int n = bh & 7;
    int q = blockIdx.x * QTILE + threadIdx.x;
    const float* Qp = Q + ((size_t)bh * S_ + q) * DK_;
    const float* Kbase = K + (size_t)bh * S_ * DK_;
    const float* Vbase = V + (size_t)bh * S_ * DK_;
    const int* mrow = mask + b * S_;

    float qreg[DK_];
    {
        const float4* Qp4 = (const float4*)Qp;
        #pragma unroll
        for (int d4 = 0; d4 < DK_ / 4; d4++) {
            float4 tt = Qp4[d4];
            qreg[d4 * 4 + 0] = tt.x * 0.125f;   // fold 1/sqrt(DK) into q
            qreg[d4 * 4 + 1] = tt.y * 0.125f;
            qreg[d4 * 4 + 2] = tt.z * 0.125f;
            qreg[d4 * 4 + 3] = tt.w * 0.125f;
        }
    }
    float o[DK_];
    #pragma unroll
    for (int d = 0; d < DK_; d++) o[d] = 0.f;
    float m_i = NEG_INF_, l_i = 0.f;

    __shared__ float Ks[KTILE][DK_];
    __shared__ float Vs[KTILE][DK_];
    __shared__ float msk[KTILE];

    for (int kt = 0; kt < S_; kt += KTILE) {
        __syncthreads();
        {
            const float4* Ksrc = (const float4*)(Kbase + (size_t)kt * DK_);
            const float4* Vsrc = (const float4*)(Vbase + (size_t)kt * DK_);
            float4* Kdst = (float4*)&Ks[0][0];
            float4* Vdst = (float4*)&Vs[0][0];
            #pragma unroll
            for (int i = 0; i < (KTILE * DK_ / 4) / 128; i++) {
                int idx = threadIdx.x + i * 128;
                Kdst[idx] = Ksrc[idx];
                Vdst[idx] = Vsrc[idx];
            }
            if (threadIdx.x < KTILE)
                msk[threadIdx.x] = (float)mrow[kt + threadIdx.x];
        }
        __syncthreads();

        float s[KTILE];
        #pragma unroll
        for (int k = 0; k < KTILE; k++) {
            float a0 = 0.f, a1 = 0.f, a2 = 0.f, a3 = 0.f;
            const float4* K4 = (const float4*)&Ks[k][0];
            #pragma unroll
            for (int d4 = 0; d4 < DK_ / 4; d4++) {
                float4 kv = K4[d4];
                a0 += qreg[d4 * 4 + 0] * kv.x;
                a1 += qreg[d4 * 4 + 1] * kv.y;
                a2 += qreg[d4 * 4 + 2] * kv.z;
                a3 += qreg[d4 * 4 + 3] * kv.w;
            }
            float sc = (a0 + a1) + (a2 + a3);
            s[k] = (msk[k] != 0.f) ? sc : NEG_INF_;   // m*s + (1-m)*NEG_INF
        }
        float mt = NEG_INF_;
        #pragma unroll
        for (int k = 0; k < KTILE; k++) mt = fmaxf(mt, s[k]);
        float m_new = fmaxf(m_i, mt);
        float alpha = __expf(m_i - m_new);
        l_i *= alpha;
        #pragma unroll
        for (int d = 0; d < DK_; d++) o[d] *= alpha;
        #pragma unroll
        for (int k = 0; k < KTILE; k++) {
            float p = __expf(s[k] - m_new);
            l_i += p;
            const float4* V4 = (const float4*)&Vs[k][0];
            #pragma unroll
            for (int d4 = 0; d4 < DK_ / 4; d4++) {
                float4 vv = V4[d4];
                o[d4 * 4 + 0] += p * vv.x;
                o[d4 * 4 + 1] += p * vv.y;
                o[d4 * 4 + 2] += p * vv.z;
                o[d4 * 4 + 3] += p * vv.w;
            }
        }
        m_i = m_new;
    }
    float inv = 1.f / l_i;
    float* hp = Hout + ((size_t)b * S_ + q) * H_ + n * DK_;
    float4* hp4 = (float4*)hp;
    #pragma unroll
    for (int d4 = 0; d4 < DK_ / 4; d4++) {
        float4 tt;
        tt.x = o[d4 * 4 + 0] * inv; tt.y = o[d4 * 4 + 1] * inv;
        tt.z = o[d4 * 4 + 2] * inv; tt.w = o[d4 * 4 + 3] * inv;
        hp4[d4] = tt;
    }
}

// ---------------------------------------------------------------------------
// Kernel 4: out = (h @ Wo + xn) * mask_row. Same 64x64 tiling as kernel 2.
// grid (8 colblocks, 128 rowblocks); block 256.
// ---------------------------------------------------------------------------
__global__ __launch_bounds__(256) void out_kernel(
        const float* __restrict__ Hb, const float* __restrict__ Wo,
        const float* __restrict__ xn, const int* __restrict__ mask,
        float* __restrict__ out) {
    int j0 = blockIdx.x * 64;
    int row0 = blockIdx.y * 64;
    __shared__ float As[16][65];
    __shared__ float Bs[16][65];
    int t = threadIdx.x, tx = t & 15, ty = t >> 4;
    float acc[4][4] = {};
    for (int k0 = 0; k0 < H_; k0 += 16) {
        #pragma unroll
        for (int i = 0; i < 4; i++) {
            int idx = t + i * 256;
            int c = idx & 15, r = idx >> 4;
            As[c][r] = Hb[(size_t)(row0 + r) * H_ + k0 + c];
        }
        #pragma unroll
        for (int i = 0; i < 4; i++) {
            int idx = t + i * 256;
            int d = idx & 63, kk = idx >> 6;
            Bs[kk][d] = Wo[(size_t)(k0 + kk) * H_ + j0 + d];
        }
        __syncthreads();
        #pragma unroll
        for (int kk = 0; kk < 16; kk++) {
            float a[4], bb[4];
            #pragma unroll
            for (int i = 0; i < 4; i++) a[i] = As[kk][ty * 4 + i];
            #pragma unroll
            for (int j = 0; j < 4; j++) bb[j] = Bs[kk][tx * 4 + j];
            #pragma unroll
            for (int i = 0; i < 4; i++)
                #pragma unroll
                for (int j = 0; j < 4; j++) acc[i][j] += a[i] * bb[j];
        }
        __syncthreads();
    }
    #pragma unroll
    for (int i = 0; i < 4; i++) {
        int r = row0 + ty * 4 + i;
        float mf = (float)mask[r];          // r == b*S + s, mask is flat (B,S)
        size_t o = (size_t)r * H_ + j0 + tx * 4;
        #pragma unroll
        for (int j = 0; j < 4; j++) out[o + j] = (acc[i][j] + xn[o + j]) * mf;
    }
}

// ---------------------------------------------------------------------------
extern "C" void kernel_launch(void* const* d_in, const int* in_sizes, int n_in,
                              void* d_out, int out_size, void* d_ws, size_t ws_size,
                              hipStream_t stream) {
    const float* x     = (const float*)d_in[0];
    const int*   mask  = (const int*)d_in[1];
    const float* Wq    = (const float*)d_in[2];
    const float* Wk    = (const float*)d_in[3];
    const float* Wv    = (const float*)d_in[4];
    const float* Wo    = (const float*)d_in[5];
    const float* gamma = (const float*)d_in[6];
    const float* beta  = (const float*)d_in[7];
    float* out = (float*)d_out;

    size_t nelem = (size_t)NROWS_ * H_;   // 4M floats = 16 MB each
    float* xn = (float*)d_ws;
    float* Qb = xn + nelem;
    float* Kb = Qb + nelem;
    float* Vb = Kb + nelem;
    float* Hb = Vb + nelem;

    ln_kernel<<<NROWS_, 256, 0, stream>>>(x, gamma, beta, xn);
    qkv_kernel<<<dim3(HEADS_, NROWS_ / 64, 3), 256, 0, stream>>>(
        xn, Wq, Wk, Wv, Qb, Kb, Vb);
    attn_kernel<<<dim3(S_ / QTILE, B_ * HEADS_), QTILE, 0, stream>>>(
        Qb, Kb, Vb, mask, Hb);
    out_kernel<<<dim3(H_ / 64, NROWS_ / 64), 256, 0, stream>>>(
        Hb, Wo, xn, mask, out);
}

// Round 2
// 657.689 us; speedup vs baseline: 3.1002x; 3.1002x over previous
//
#include <hip/hip_runtime.h>
#include <math.h>

#define B_ 4
#define S_ 2048
#define H_ 512
#define HEADS_ 8
#define DK_ 64
#define NROWS_ (B_*S_)          // 8192
#define LN_EPS_ 1e-5f
#define NEG_INF_ -1e30f

typedef short s8v __attribute__((ext_vector_type(8)));   // 8 bf16 in 4 VGPRs
typedef float f4v __attribute__((ext_vector_type(4)));

__device__ __forceinline__ unsigned short f2bf(float f) {
    unsigned int u = __float_as_uint(f);
    u += 0x7FFFu + ((u >> 16) & 1u);     // round-to-nearest-even
    return (unsigned short)(u >> 16);
}

// ---------------------------------------------------------------------------
// Kernel 1: LayerNorm (unchanged).
// ---------------------------------------------------------------------------
__global__ __launch_bounds__(256) void ln_kernel(
        const float* __restrict__ x, const float* __restrict__ gamma,
        const float* __restrict__ beta, float* __restrict__ xn) {
    int row = blockIdx.x;
    const float* xr = x + (size_t)row * H_;
    int t = threadIdx.x;
    float v0 = xr[t], v1 = xr[t + 256];
    float s = v0 + v1, ss = v0 * v0 + v1 * v1;
    #pragma unroll
    for (int i = 1; i < 64; i <<= 1) {
        s  += __shfl_xor(s, i, 64);
        ss += __shfl_xor(ss, i, 64);
    }
    __shared__ float red[8];
    int w = t >> 6, lane = t & 63;
    if (lane == 0) { red[w] = s; red[w + 4] = ss; }
    __syncthreads();
    s  = red[0] + red[1] + red[2] + red[3];
    ss = red[4] + red[5] + red[6] + red[7];
    float mu  = s * (1.f / 512.f);
    float var = ss * (1.f / 512.f) - mu * mu;
    float rstd = rsqrtf(var + LN_EPS_);
    size_t o = (size_t)row * H_;
    xn[o + t]       = (v0 - mu) * rstd * gamma[t]       + beta[t];
    xn[o + t + 256] = (v1 - mu) * rstd * gamma[t + 256] + beta[t + 256];
}

// ---------------------------------------------------------------------------
// Kernel 2: QKV projection (fp32 compute), epilogue emits:
//   Qb bf16 (B,HEADS,S,DK) pre-scaled by 1/sqrt(DK)
//   Kb bf16 (B,HEADS,S,DK)
//   Vt bf16 (B,HEADS,DK,S)   <- transposed for the O^T = V^T P^T MFMA trick
// ---------------------------------------------------------------------------
__global__ __launch_bounds__(256) void qkv_kernel(
        const float* __restrict__ xn,
        const float* __restrict__ Wq, const float* __restrict__ Wk,
        const float* __restrict__ Wv,
        unsigned short* __restrict__ Qb, unsigned short* __restrict__ Kb,
        unsigned short* __restrict__ Vt) {
    const float* W = (blockIdx.z == 0) ? Wq : (blockIdx.z == 1) ? Wk : Wv;
    int n = blockIdx.x;                // head index; col block = n*64
    int row0 = blockIdx.y * 64;
    __shared__ float As[16][65];
    __shared__ float Bs[16][65];
    int t = threadIdx.x;
    int tx = t & 15, ty = t >> 4;
    float acc[4][4] = {};
    const float* Wn = W + (size_t)n * H_ * DK_;   // [h][d], 512x64 row-major
    for (int k0 = 0; k0 < H_; k0 += 16) {
        #pragma unroll
        for (int i = 0; i < 4; i++) {
            int idx = t + i * 256;
            int c = idx & 15, r = idx >> 4;
            As[c][r] = xn[(size_t)(row0 + r) * H_ + k0 + c];
        }
        #pragma unroll
        for (int i = 0; i < 4; i++) {
            int idx = t + i * 256;
            int d = idx & 63, kk = idx >> 6;
            Bs[kk][d] = Wn[(size_t)(k0 + kk) * DK_ + d];
        }
        __syncthreads();
        #pragma unroll
        for (int kk = 0; kk < 16; kk++) {
            float a[4], bb[4];
            #pragma unroll
            for (int i = 0; i < 4; i++) a[i] = As[kk][ty * 4 + i];
            #pragma unroll
            for (int j = 0; j < 4; j++) bb[j] = Bs[kk][tx * 4 + j];
            #pragma unroll
            for (int i = 0; i < 4; i++)
                #pragma unroll
                for (int j = 0; j < 4; j++) acc[i][j] += a[i] * bb[j];
        }
        __syncthreads();
    }
    if (blockIdx.z == 2) {            // V -> transposed bf16
        #pragma unroll
        for (int i = 0; i < 4; i++) {
            int r = row0 + ty * 4 + i;
            int b = r >> 11, srow = r & 2047;
            size_t base = (size_t)(b * HEADS_ + n) * DK_ * S_;
            #pragma unroll
            for (int j = 0; j < 4; j++)
                Vt[base + (size_t)(tx * 4 + j) * S_ + srow] = f2bf(acc[i][j]);
        }
    } else {
        unsigned short* Out = (blockIdx.z == 0) ? Qb : Kb;
        float scale = (blockIdx.z == 0) ? 0.125f : 1.0f;   // fold 1/sqrt(DK) into Q
        #pragma unroll
        for (int i = 0; i < 4; i++) {
            int r = row0 + ty * 4 + i;
            int b = r >> 11, srow = r & 2047;
            size_t base = (((size_t)(b * HEADS_ + n)) * S_ + srow) * DK_ + tx * 4;
            #pragma unroll
            for (int j = 0; j < 4; j++) Out[base + j] = f2bf(acc[i][j] * scale);
        }
    }
}

// ---------------------------------------------------------------------------
// Kernel 3: flash attention, bf16 MFMA 16x16x32.
// Block = 256 threads = 4 independent waves; wave owns 16 q-rows.
// Per 32-key tile: 4 MFMAs QK^T (2 key-subtiles x 2 dk-chunks),
// shuffle-reduced online softmax (key dim = lane&15), P via per-wave LDS,
// 4 MFMAs for O^T = V^T P^T (full 32-key K-dim per MFMA).
// grid (S/64, B*HEADS). No __syncthreads anywhere.
// ---------------------------------------------------------------------------
__global__ __launch_bounds__(256) void attn_kernel(
        const unsigned short* __restrict__ Qb,
        const unsigned short* __restrict__ Kb,
        const unsigned short* __restrict__ Vt,
        const int* __restrict__ mask,
        float* __restrict__ Hout) {
    __shared__ unsigned short Pb[4][16][32];   // per-wave P tile, q-major
    __shared__ float stats[4][16];             // per-wave per-q redistribution

    int wv = threadIdx.x >> 6;
    int L  = threadIdx.x & 63;
    int c  = L & 15;            // MFMA n/col index (key or q)
    int g  = L >> 4;            // quad
    int bh = blockIdx.y;
    int b  = bh >> 3, n = bh & 7;
    int q0 = blockIdx.x * 64 + wv * 16;

    const unsigned short* Qbase = Qb + ((size_t)bh * S_) * DK_;
    const unsigned short* Kbase = Kb + ((size_t)bh * S_) * DK_;
    const unsigned short* Vbase = Vt + (size_t)bh * DK_ * S_;
    const int* mrow = mask + b * S_;

    // Q fragments: A[m=c][k=g*8+j], two dk-chunks of 32
    s8v qf0 = *(const s8v*)(Qbase + (size_t)(q0 + c) * DK_ + g * 8);
    s8v qf1 = *(const s8v*)(Qbase + (size_t)(q0 + c) * DK_ + 32 + g * 8);

    f4v acc[4];                 // O^T accum: d = dsub*16 + g*4 + r, q = q0 + c
    #pragma unroll
    for (int i = 0; i < 4; i++) acc[i] = (f4v){0.f, 0.f, 0.f, 0.f};
    float m4[4] = {NEG_INF_, NEG_INF_, NEG_INF_, NEG_INF_};
    float l4[4] = {0.f, 0.f, 0.f, 0.f};

    for (int kt = 0; kt < S_; kt += 32) {
        const unsigned short* Krow = Kbase + (size_t)kt * DK_;
        f4v s0 = (f4v){0.f, 0.f, 0.f, 0.f};
        f4v s1 = (f4v){0.f, 0.f, 0.f, 0.f};
        {   // B[k=g*8+j][n=c] = K[key][dk]
            s8v kf;
            kf = *(const s8v*)(Krow + (size_t)c * DK_ + g * 8);
            s0 = __builtin_amdgcn_mfma_f32_16x16x32_bf16(qf0, kf, s0, 0, 0, 0);
            kf = *(const s8v*)(Krow + (size_t)c * DK_ + 32 + g * 8);
            s0 = __builtin_amdgcn_mfma_f32_16x16x32_bf16(qf1, kf, s0, 0, 0, 0);
            kf = *(const s8v*)(Krow + (size_t)(16 + c) * DK_ + g * 8);
            s1 = __builtin_amdgcn_mfma_f32_16x16x32_bf16(qf0, kf, s1, 0, 0, 0);
            kf = *(const s8v*)(Krow + (size_t)(16 + c) * DK_ + 32 + g * 8);
            s1 = __builtin_amdgcn_mfma_f32_16x16x32_bf16(qf1, kf, s1, 0, 0, 0);
        }
        int mk0 = mrow[kt + c];
        int mk1 = mrow[kt + 16 + c];
        float mt[4], p0[4], p1[4], sum[4], alpha[4];
        #pragma unroll
        for (int r = 0; r < 4; r++) {
            s0[r] = mk0 ? s0[r] : NEG_INF_;
            s1[r] = mk1 ? s1[r] : NEG_INF_;
            mt[r] = fmaxf(s0[r], s1[r]);
        }
        #pragma unroll
        for (int off = 1; off < 16; off <<= 1)
            #pragma unroll
            for (int r = 0; r < 4; r++) mt[r] = fmaxf(mt[r], __shfl_xor(mt[r], off, 64));
        #pragma unroll
        for (int r = 0; r < 4; r++) {
            float mnew = fmaxf(m4[r], mt[r]);
            alpha[r] = __expf(m4[r] - mnew);
            p0[r] = __expf(s0[r] - mnew);
            p1[r] = __expf(s1[r] - mnew);
            sum[r] = p0[r] + p1[r];
            m4[r] = mnew;
        }
        #pragma unroll
        for (int off = 1; off < 16; off <<= 1)
            #pragma unroll
            for (int r = 0; r < 4; r++) sum[r] += __shfl_xor(sum[r], off, 64);
        #pragma unroll
        for (int r = 0; r < 4; r++) l4[r] = l4[r] * alpha[r] + sum[r];

        // redistribute alpha: score layout q=4g+r -> O^T layout q=c
        if (c == 0) {
            #pragma unroll
            for (int r = 0; r < 4; r++) stats[wv][4 * g + r] = alpha[r];
        }
        // write P (q-major [16][32]) as bf16
        #pragma unroll
        for (int r = 0; r < 4; r++) {
            Pb[wv][g * 4 + r][c]      = f2bf(p0[r]);
            Pb[wv][g * 4 + r][16 + c] = f2bf(p1[r]);
        }
        __asm__ volatile("s_waitcnt lgkmcnt(0)" ::: "memory");
        float av = stats[wv][c];
        #pragma unroll
        for (int i = 0; i < 4; i++)
            #pragma unroll
            for (int r = 0; r < 4; r++) acc[i][r] *= av;

        // O^T += V^T . P^T : A[m=c][k=g*8+j]=Vt[d][key], B[k][n=c]=P[q=c][key]
        s8v pf = *(const s8v*)(&Pb[wv][c][g * 8]);
        const unsigned short* Vrow = Vbase + kt;
        #pragma unroll
        for (int dsub = 0; dsub < 4; dsub++) {
            s8v vf = *(const s8v*)(Vrow + (size_t)(dsub * 16 + c) * S_ + g * 8);
            acc[dsub] = __builtin_amdgcn_mfma_f32_16x16x32_bf16(vf, pf, acc[dsub], 0, 0, 0);
        }
    }

    // final: divide by l (redistribute to q=c layout), store
    if (c == 0) {
        #pragma unroll
        for (int r = 0; r < 4; r++) stats[wv][4 * g + r] = l4[r];
    }
    __asm__ volatile("s_waitcnt lgkmcnt(0)" ::: "memory");
    float inv = 1.f / stats[wv][c];
    float* hp = Hout + ((size_t)(b * S_ + q0 + c)) * H_ + n * DK_ + g * 4;
    #pragma unroll
    for (int dsub = 0; dsub < 4; dsub++) {
        float4 o;
        o.x = acc[dsub][0] * inv; o.y = acc[dsub][1] * inv;
        o.z = acc[dsub][2] * inv; o.w = acc[dsub][3] * inv;
        *(float4*)(hp + dsub * 16) = o;
    }
}

// ---------------------------------------------------------------------------
// Kernel 4: out = (h @ Wo + xn) * mask_row (unchanged fp32).
// ---------------------------------------------------------------------------
__global__ __launch_bounds__(256) void out_kernel(
        const float* __restrict__ Hb, const float* __restrict__ Wo,
        const float* __restrict__ xn, const int* __restrict__ mask,
        float* __restrict__ out) {
    int j0 = blockIdx.x * 64;
    int row0 = blockIdx.y * 64;
    __shared__ float As[16][65];
    __shared__ float Bs[16][65];
    int t = threadIdx.x, tx = t & 15, ty = t >> 4;
    float acc[4][4] = {};
    for (int k0 = 0; k0 < H_; k0 += 16) {
        #pragma unroll
        for (int i = 0; i < 4; i++) {
            int idx = t + i * 256;
            int c = idx & 15, r = idx >> 4;
            As[c][r] = Hb[(size_t)(row0 + r) * H_ + k0 + c];
        }
        #pragma unroll
        for (int i = 0; i < 4; i++) {
            int idx = t + i * 256;
            int d = idx & 63, kk = idx >> 6;
            Bs[kk][d] = Wo[(size_t)(k0 + kk) * H_ + j0 + d];
        }
        __syncthreads();
        #pragma unroll
        for (int kk = 0; kk < 16; kk++) {
            float a[4], bb[4];
            #pragma unroll
            for (int i = 0; i < 4; i++) a[i] = As[kk][ty * 4 + i];
            #pragma unroll
            for (int j = 0; j < 4; j++) bb[j] = Bs[kk][tx * 4 + j];
            #pragma unroll
            for (int i = 0; i < 4; i++)
                #pragma unroll
                for (int j = 0; j < 4; j++) acc[i][j] += a[i] * bb[j];
        }
        __syncthreads();
    }
    #pragma unroll
    for (int i = 0; i < 4; i++) {
        int r = row0 + ty * 4 + i;
        float mf = (float)mask[r];
        size_t o = (size_t)r * H_ + j0 + tx * 4;
        #pragma unroll
        for (int j = 0; j < 4; j++) out[o + j] = (acc[i][j] + xn[o + j]) * mf;
    }
}

// ---------------------------------------------------------------------------
extern "C" void kernel_launch(void* const* d_in, const int* in_sizes, int n_in,
                              void* d_out, int out_size, void* d_ws, size_t ws_size,
                              hipStream_t stream) {
    const float* x     = (const float*)d_in[0];
    const int*   mask  = (const int*)d_in[1];
    const float* Wq    = (const float*)d_in[2];
    const float* Wk    = (const float*)d_in[3];
    const float* Wv    = (const float*)d_in[4];
    const float* Wo    = (const float*)d_in[5];
    const float* gamma = (const float*)d_in[6];
    const float* beta  = (const float*)d_in[7];
    float* out = (float*)d_out;

    size_t nelem = (size_t)NROWS_ * H_;   // 4M elements
    char* ws = (char*)d_ws;
    float*          xn = (float*)ws;                       ws += nelem * 4;
    float*          Hb = (float*)ws;                       ws += nelem * 4;
    unsigned short* Qb = (unsigned short*)ws;              ws += nelem * 2;
    unsigned short* Kb = (unsigned short*)ws;              ws += nelem * 2;
    unsigned short* Vt = (unsigned short*)ws;

    ln_kernel<<<NROWS_, 256, 0, stream>>>(x, gamma, beta, xn);
    qkv_kernel<<<dim3(HEADS_, NROWS_ / 64, 3), 256, 0, stream>>>(
        xn, Wq, Wk, Wv, Qb, Kb, Vt);
    attn_kernel<<<dim3(S_ / 64, B_ * HEADS_), 256, 0, stream>>>(
        Qb, Kb, Vt, mask, Hb);
    out_kernel<<<dim3(H_ / 64, NROWS_ / 64), 256, 0, stream>>>(
        Hb, Wo, xn, mask, out);
}

// Round 3
// 387.032 us; speedup vs baseline: 5.2682x; 1.6993x over previous
//
#include <hip/hip_runtime.h>
#include <math.h>

#define B_ 4
#define S_ 2048
#define H_ 512
#define HEADS_ 8
#define DK_ 64
#define NROWS_ (B_*S_)          // 8192
#define LN_EPS_ 1e-5f
#define NEG_INF_ -1e30f

typedef short s8v __attribute__((ext_vector_type(8)));   // 8 bf16 in 4 VGPRs
typedef float f4v __attribute__((ext_vector_type(4)));

__device__ __forceinline__ unsigned short f2bf(float f) {
    unsigned int u = __float_as_uint(f);
    u += 0x7FFFu + ((u >> 16) & 1u);     // round-to-nearest-even
    return (unsigned short)(u >> 16);
}

// ---------------------------------------------------------------------------
// Kernel 0: weight transpose -> Wt (2048 x 512 bf16, row j holds W[.][j] over k)
//   rows    0..511  : Wq heads (scaled by 1/sqrt(DK))
//   rows  512..1023 : Wk heads
//   rows 1024..1535 : Wv heads
//   rows 1536..2047 : Wo columns
// grid (16,16,25), block 256. z<24: per-head (512x64) transpose, x<2 only.
// ---------------------------------------------------------------------------
__global__ __launch_bounds__(256) void wt_kernel(
        const float* __restrict__ Wq, const float* __restrict__ Wk,
        const float* __restrict__ Wv, const float* __restrict__ Wo,
        unsigned short* __restrict__ Wt) {
    __shared__ float tile[32][33];
    int z = blockIdx.z;
    int k0 = blockIdx.y * 32, c0 = blockIdx.x * 32;
    const float* src;
    int ld, drow;
    float scale = 1.f;
    if (z < 24) {
        if (blockIdx.x >= 2) return;
        int zw = z >> 3, head = z & 7;
        const float* W = (zw == 0) ? Wq : (zw == 1) ? Wk : Wv;
        if (zw == 0) scale = 0.125f;
        src = W + (size_t)head * H_ * DK_;
        ld = DK_;
        drow = zw * 512 + head * 64;
    } else {
        src = Wo; ld = H_; drow = 1536;
    }
    int tx = threadIdx.x & 31, ty = threadIdx.x >> 5;
    #pragma unroll
    for (int i = 0; i < 4; i++)
        tile[ty * 4 + i][tx] = src[(size_t)(k0 + ty * 4 + i) * ld + c0 + tx];
    __syncthreads();
    #pragma unroll
    for (int i = 0; i < 4; i++) {
        int cc = ty * 4 + i;
        Wt[(size_t)(drow + c0 + cc) * 512 + k0 + tx] = f2bf(tile[tx][cc] * scale);
    }
}

// ---------------------------------------------------------------------------
// Kernel 1: LayerNorm -> xn fp32 (residual) + xnb bf16 (GEMM input).
// ---------------------------------------------------------------------------
__global__ __launch_bounds__(256) void ln_kernel(
        const float* __restrict__ x, const float* __restrict__ gamma,
        const float* __restrict__ beta, float* __restrict__ xn,
        unsigned short* __restrict__ xnb) {
    int row = blockIdx.x;
    const float* xr = x + (size_t)row * H_;
    int t = threadIdx.x;
    float v0 = xr[t], v1 = xr[t + 256];
    float s = v0 + v1, ss = v0 * v0 + v1 * v1;
    #pragma unroll
    for (int i = 1; i < 64; i <<= 1) {
        s  += __shfl_xor(s, i, 64);
        ss += __shfl_xor(ss, i, 64);
    }
    __shared__ float red[8];
    int w = t >> 6, lane = t & 63;
    if (lane == 0) { red[w] = s; red[w + 4] = ss; }
    __syncthreads();
    s  = red[0] + red[1] + red[2] + red[3];
    ss = red[4] + red[5] + red[6] + red[7];
    float mu  = s * (1.f / 512.f);
    float var = ss * (1.f / 512.f) - mu * mu;
    float rstd = rsqrtf(var + LN_EPS_);
    size_t o = (size_t)row * H_;
    float y0 = (v0 - mu) * rstd * gamma[t]       + beta[t];
    float y1 = (v1 - mu) * rstd * gamma[t + 256] + beta[t + 256];
    xn[o + t] = y0;           xn[o + t + 256] = y1;
    xnb[o + t] = f2bf(y0);    xnb[o + t + 256] = f2bf(y1);
}

// ---------------------------------------------------------------------------
// Shared MFMA GEMM tile loop: C(128x128) = A[r0..r0+127][0..511] . Bt^T
// A, Bt row-major bf16 with K=512 contiguous. Block 256 = 4 waves, each wave
// owns a 64x64 sub-tile (4x4 16x16x32 MFMAs per BK=32 chunk, 8 ds_read_b128).
// LDS pad +8 elems: fragment reads conflict-free, writes <=3-way.
// ---------------------------------------------------------------------------
#define BK_ 32
__device__ __forceinline__ void gemm_tile(
        const unsigned short* __restrict__ A,
        const unsigned short* __restrict__ Bt,
        int r0, int j0, f4v acc[4][4]) {
    __shared__ unsigned short As[128][BK_ + 8];
    __shared__ unsigned short Bs[128][BK_ + 8];
    int t = threadIdx.x;
    int wv = t >> 6, L = t & 63, c = L & 15, g = L >> 4;
    int m_base = (wv & 1) * 64, n_base = (wv >> 1) * 64;
    #pragma unroll
    for (int i = 0; i < 4; i++)
        #pragma unroll
        for (int j = 0; j < 4; j++) acc[i][j] = (f4v){0.f, 0.f, 0.f, 0.f};
    for (int k0 = 0; k0 < 512; k0 += BK_) {
        __syncthreads();
        #pragma unroll
        for (int i = 0; i < 2; i++) {
            int idx = t + i * 256;
            int m = idx >> 2, k8 = idx & 3;
            s8v va = *(const s8v*)(A  + (size_t)(r0 + m) * 512 + k0 + k8 * 8);
            s8v vb = *(const s8v*)(Bt + (size_t)(j0 + m) * 512 + k0 + k8 * 8);
            *(s8v*)(&As[m][k8 * 8]) = va;
            *(s8v*)(&Bs[m][k8 * 8]) = vb;
        }
        __syncthreads();
        s8v a[4], b[4];
        #pragma unroll
        for (int i = 0; i < 4; i++)
            a[i] = *(const s8v*)(&As[m_base + i * 16 + c][g * 8]);
        #pragma unroll
        for (int j = 0; j < 4; j++)
            b[j] = *(const s8v*)(&Bs[n_base + j * 16 + c][g * 8]);
        #pragma unroll
        for (int i = 0; i < 4; i++)
            #pragma unroll
            for (int j = 0; j < 4; j++)
                acc[i][j] = __builtin_amdgcn_mfma_f32_16x16x32_bf16(
                    a[i], b[j], acc[i][j], 0, 0, 0);
    }
}

// ---------------------------------------------------------------------------
// Kernel 2: QKV = xnb @ Wt^T; epilogue scatters bf16 Qb/Kb (B,H,S,DK) and
// Vt (B,H,DK,S). grid (12, 64).
// ---------------------------------------------------------------------------
__global__ __launch_bounds__(256) void qkv_gemm(
        const unsigned short* __restrict__ xnb,
        const unsigned short* __restrict__ Wt,
        unsigned short* __restrict__ Qb, unsigned short* __restrict__ Kb,
        unsigned short* __restrict__ Vt) {
    f4v acc[4][4];
    int r0 = blockIdx.y * 128, j0 = blockIdx.x * 128;
    gemm_tile(xnb, Wt, r0, j0, acc);
    int t = threadIdx.x;
    int wv = t >> 6, L = t & 63, c = L & 15, g = L >> 4;
    int mrow = r0 + (wv & 1) * 64 + g * 4;
    int ncol = j0 + (wv >> 1) * 64 + c;
    int z = j0 >> 9;                       // uniform per block
    #pragma unroll
    for (int msub = 0; msub < 4; msub++) {
        #pragma unroll
        for (int nsub = 0; nsub < 4; nsub++) {
            int col = ncol + nsub * 16;
            int hd = (col >> 6) & 7, d = col & 63;
            #pragma unroll
            for (int rr = 0; rr < 4; rr++) {
                int row = mrow + msub * 16 + rr;
                int b = row >> 11, srow = row & 2047;
                unsigned short val = f2bf(acc[msub][nsub][rr]);
                if (z == 2)
                    Vt[(size_t)(b * HEADS_ + hd) * DK_ * S_ + (size_t)d * S_ + srow] = val;
                else if (z == 1)
                    Kb[((size_t)(b * HEADS_ + hd) * S_ + srow) * DK_ + d] = val;
                else
                    Qb[((size_t)(b * HEADS_ + hd) * S_ + srow) * DK_ + d] = val;
            }
        }
    }
}

// ---------------------------------------------------------------------------
// Kernel 3: flash attention, bf16 MFMA 16x16x32 (round-2 design, hb out bf16).
// ---------------------------------------------------------------------------
__global__ __launch_bounds__(256) void attn_kernel(
        const unsigned short* __restrict__ Qb,
        const unsigned short* __restrict__ Kb,
        const unsigned short* __restrict__ Vt,
        const int* __restrict__ mask,
        unsigned short* __restrict__ hb) {
    __shared__ unsigned short Pb[4][16][32];
    __shared__ float stats[4][16];

    int wv = threadIdx.x >> 6;
    int L  = threadIdx.x & 63;
    int c  = L & 15;
    int g  = L >> 4;
    int bh = blockIdx.y;
    int b  = bh >> 3, n = bh & 7;
    int q0 = blockIdx.x * 64 + wv * 16;

    const unsigned short* Qbase = Qb + ((size_t)bh * S_) * DK_;
    const unsigned short* Kbase = Kb + ((size_t)bh * S_) * DK_;
    const unsigned short* Vbase = Vt + (size_t)bh * DK_ * S_;
    const int* mrow = mask + b * S_;

    s8v qf0 = *(const s8v*)(Qbase + (size_t)(q0 + c) * DK_ + g * 8);
    s8v qf1 = *(const s8v*)(Qbase + (size_t)(q0 + c) * DK_ + 32 + g * 8);

    f4v acc[4];
    #pragma unroll
    for (int i = 0; i < 4; i++) acc[i] = (f4v){0.f, 0.f, 0.f, 0.f};
    float m4[4] = {NEG_INF_, NEG_INF_, NEG_INF_, NEG_INF_};
    float l4[4] = {0.f, 0.f, 0.f, 0.f};

    for (int kt = 0; kt < S_; kt += 32) {
        const unsigned short* Krow = Kbase + (size_t)kt * DK_;
        f4v s0 = (f4v){0.f, 0.f, 0.f, 0.f};
        f4v s1 = (f4v){0.f, 0.f, 0.f, 0.f};
        {
            s8v kf;
            kf = *(const s8v*)(Krow + (size_t)c * DK_ + g * 8);
            s0 = __builtin_amdgcn_mfma_f32_16x16x32_bf16(qf0, kf, s0, 0, 0, 0);
            kf = *(const s8v*)(Krow + (size_t)c * DK_ + 32 + g * 8);
            s0 = __builtin_amdgcn_mfma_f32_16x16x32_bf16(qf1, kf, s0, 0, 0, 0);
            kf = *(const s8v*)(Krow + (size_t)(16 + c) * DK_ + g * 8);
            s1 = __builtin_amdgcn_mfma_f32_16x16x32_bf16(qf0, kf, s1, 0, 0, 0);
            kf = *(const s8v*)(Krow + (size_t)(16 + c) * DK_ + 32 + g * 8);
            s1 = __builtin_amdgcn_mfma_f32_16x16x32_bf16(qf1, kf, s1, 0, 0, 0);
        }
        int mk0 = mrow[kt + c];
        int mk1 = mrow[kt + 16 + c];
        float mt[4], p0[4], p1[4], sum[4], alpha[4];
        #pragma unroll
        for (int r = 0; r < 4; r++) {
            s0[r] = mk0 ? s0[r] : NEG_INF_;
            s1[r] = mk1 ? s1[r] : NEG_INF_;
            mt[r] = fmaxf(s0[r], s1[r]);
        }
        #pragma unroll
        for (int off = 1; off < 16; off <<= 1)
            #pragma unroll
            for (int r = 0; r < 4; r++) mt[r] = fmaxf(mt[r], __shfl_xor(mt[r], off, 64));
        #pragma unroll
        for (int r = 0; r < 4; r++) {
            float mnew = fmaxf(m4[r], mt[r]);
            alpha[r] = __expf(m4[r] - mnew);
            p0[r] = __expf(s0[r] - mnew);
            p1[r] = __expf(s1[r] - mnew);
            sum[r] = p0[r] + p1[r];
            m4[r] = mnew;
        }
        #pragma unroll
        for (int off = 1; off < 16; off <<= 1)
            #pragma unroll
            for (int r = 0; r < 4; r++) sum[r] += __shfl_xor(sum[r], off, 64);
        #pragma unroll
        for (int r = 0; r < 4; r++) l4[r] = l4[r] * alpha[r] + sum[r];

        if (c == 0) {
            #pragma unroll
            for (int r = 0; r < 4; r++) stats[wv][4 * g + r] = alpha[r];
        }
        #pragma unroll
        for (int r = 0; r < 4; r++) {
            Pb[wv][g * 4 + r][c]      = f2bf(p0[r]);
            Pb[wv][g * 4 + r][16 + c] = f2bf(p1[r]);
        }
        __asm__ volatile("s_waitcnt lgkmcnt(0)" ::: "memory");
        float av = stats[wv][c];
        #pragma unroll
        for (int i = 0; i < 4; i++)
            #pragma unroll
            for (int r = 0; r < 4; r++) acc[i][r] *= av;

        s8v pf = *(const s8v*)(&Pb[wv][c][g * 8]);
        const unsigned short* Vrow = Vbase + kt;
        #pragma unroll
        for (int dsub = 0; dsub < 4; dsub++) {
            s8v vf = *(const s8v*)(Vrow + (size_t)(dsub * 16 + c) * S_ + g * 8);
            acc[dsub] = __builtin_amdgcn_mfma_f32_16x16x32_bf16(vf, pf, acc[dsub], 0, 0, 0);
        }
    }

    if (c == 0) {
        #pragma unroll
        for (int r = 0; r < 4; r++) stats[wv][4 * g + r] = l4[r];
    }
    __asm__ volatile("s_waitcnt lgkmcnt(0)" ::: "memory");
    float inv = 1.f / stats[wv][c];
    unsigned short* hp = hb + (size_t)(b * S_ + q0 + c) * H_ + n * DK_ + g * 4;
    #pragma unroll
    for (int dsub = 0; dsub < 4; dsub++) {
        unsigned int lo = (unsigned int)f2bf(acc[dsub][0] * inv)
                        | ((unsigned int)f2bf(acc[dsub][1] * inv) << 16);
        unsigned int hi = (unsigned int)f2bf(acc[dsub][2] * inv)
                        | ((unsigned int)f2bf(acc[dsub][3] * inv) << 16);
        uint2 pk; pk.x = lo; pk.y = hi;
        *(uint2*)(hp + dsub * 16) = pk;
    }
}

// ---------------------------------------------------------------------------
// Kernel 4: out = (hb @ Wot^T + xn) * mask. grid (4, 64).
// ---------------------------------------------------------------------------
__global__ __launch_bounds__(256) void out_gemm(
        const unsigned short* __restrict__ hb,
        const unsigned short* __restrict__ Wot,
        const float* __restrict__ xn, const int* __restrict__ mask,
        float* __restrict__ out) {
    f4v acc[4][4];
    int r0 = blockIdx.y * 128, j0 = blockIdx.x * 128;
    gemm_tile(hb, Wot, r0, j0, acc);
    int t = threadIdx.x;
    int wv = t >> 6, L = t & 63, c = L & 15, g = L >> 4;
    int mrow = r0 + (wv & 1) * 64 + g * 4;
    int ncol = j0 + (wv >> 1) * 64 + c;
    #pragma unroll
    for (int msub = 0; msub < 4; msub++) {
        #pragma unroll
        for (int rr = 0; rr < 4; rr++) {
            int row = mrow + msub * 16 + rr;
            float mf = (float)mask[row];
            #pragma unroll
            for (int nsub = 0; nsub < 4; nsub++) {
                int col = ncol + nsub * 16;
                size_t o = (size_t)row * H_ + col;
                out[o] = (acc[msub][nsub][rr] + xn[o]) * mf;
            }
        }
    }
}

// ---------------------------------------------------------------------------
extern "C" void kernel_launch(void* const* d_in, const int* in_sizes, int n_in,
                              void* d_out, int out_size, void* d_ws, size_t ws_size,
                              hipStream_t stream) {
    const float* x     = (const float*)d_in[0];
    const int*   mask  = (const int*)d_in[1];
    const float* Wq    = (const float*)d_in[2];
    const float* Wk    = (const float*)d_in[3];
    const float* Wv    = (const float*)d_in[4];
    const float* Wo    = (const float*)d_in[5];
    const float* gamma = (const float*)d_in[6];
    const float* beta  = (const float*)d_in[7];
    float* out = (float*)d_out;

    size_t nelem = (size_t)NROWS_ * H_;   // 4M elements
    char* ws = (char*)d_ws;
    float*          xn  = (float*)ws;          ws += nelem * 4;   // 16 MB
    unsigned short* xnb = (unsigned short*)ws; ws += nelem * 2;   // 8 MB
    unsigned short* hb  = (unsigned short*)ws; ws += nelem * 2;   // 8 MB
    unsigned short* Qb  = (unsigned short*)ws; ws += nelem * 2;   // 8 MB
    unsigned short* Kb  = (unsigned short*)ws; ws += nelem * 2;   // 8 MB
    unsigned short* Vt  = (unsigned short*)ws; ws += nelem * 2;   // 8 MB
    unsigned short* Wt  = (unsigned short*)ws;                    // 2 MB

    wt_kernel<<<dim3(16, 16, 25), 256, 0, stream>>>(Wq, Wk, Wv, Wo, Wt);
    ln_kernel<<<NROWS_, 256, 0, stream>>>(x, gamma, beta, xn, xnb);
    qkv_gemm<<<dim3(12, 64), 256, 0, stream>>>(xnb, Wt, Qb, Kb, Vt);
    attn_kernel<<<dim3(S_ / 64, B_ * HEADS_), 256, 0, stream>>>(
        Qb, Kb, Vt, mask, hb);
    out_gemm<<<dim3(4, 64), 256, 0, stream>>>(
        hb, Wt + (size_t)1536 * 512, xn, mask, out);
}